// Round 7
// baseline (146.387 us; speedup 1.0000x reference)
//
#include <hip/hip_runtime.h>
#include <stdint.h>

// Dual quantized EMA scan, chunked with redundant warmup.
// State in scaled domain Y = y*2^23: 24-bit quantize = one v_rndne.
// R7: S 1024->2048 (amp 1.094 -> 1.035, demand 427 -> 412 MB; model from
// R2-R6: dur = demand / 6.4 TB/s). At S=2048 only 256 independent waves
// exist (1/CU), so deep lookahead comes from the R4-proven LDS group ring:
// G=4 x U=32 rows x 2 arrays x 256 B = 64 KB, 48 KB of loads in flight per
// wave via counted vmcnt (16 gl_lds per group -> ladder 48/32/16/0).
// gl_lds moves 4 rows/instr: lane l -> row l>>4, 16B chunk (l&15); LDS word
// l*4 = (l>>4)*64 + (l&15)*4 = row-major [4][64], linear dest. Consumption
// ring[..][r][lane]: lanes l,l+32 same bank diff addr = 2-way = free.

constexpr int T = 8192;
constexpr int C = 256;
constexpr int S = 2048;         // chunk length (output rows per wave)
constexpr int W = 96;           // warmup length (alpha^96*|state| ~ 5e-4)
constexpr int U = 32;           // rows per group
constexpr int G = 4;            // ring depth in groups
constexpr int NCHUNK = T / S;   // 4
constexpr int CQ = 4;           // 64-channel quarters per row
constexpr int WGW = W / U;      // 3 warmup groups

constexpr float ALPHA = 0.95f;

__device__ __forceinline__ void vwait48() { asm volatile("s_waitcnt vmcnt(48)" ::: "memory"); }
__device__ __forceinline__ void vwait32() { asm volatile("s_waitcnt vmcnt(32)" ::: "memory"); }
__device__ __forceinline__ void vwait16() { asm volatile("s_waitcnt vmcnt(16)" ::: "memory"); }
__device__ __forceinline__ void vwait0()  { asm volatile("s_waitcnt vmcnt(0)"  ::: "memory"); }
__device__ __forceinline__ void lwait0()  { asm volatile("s_waitcnt lgkmcnt(0)" ::: "memory"); }

__device__ __forceinline__ void gload16(const float* g, float* l) {
  // global src is per-lane; LDS dest is wave-uniform base + lane*16 (linear).
  __builtin_amdgcn_global_load_lds((const __attribute__((address_space(1))) uint32_t*)g,
                                   (__attribute__((address_space(3))) uint32_t*)l,
                                   16, 0, 0);
}

template <bool WARM>
__device__ __forceinline__ void run_chunk(const float* __restrict__ xp,   // per-lane gl_lds src
                                          const float* __restrict__ yp,   // per-lane gl_lds src
                                          float* __restrict__ op,         // per-lane out ptr
                                          float (*ring)[2][U][64],
                                          int lane) {
  constexpr int WG = WARM ? WGW : 0;     // 3 or 0 warmup groups
  constexpr int NG = WG + S / U;         // 67 or 64 total groups
  const float Kc  = (1.0f - ALPHA) * 8388608.0f;  // (1-a) * 2^23
  const float C8  = 1.0f / 256.0f;                // 2^23 -> 2^15 domain
  const float I16 = 1.0f / 32768.0f;

  float Y0 = 0.0f, Y1 = 0.0f;

  auto issue = [&](int g) {
    const int sl = g & (G - 1);
    const float* xr = xp + (size_t)g * U * C;
    const float* yr = yp + (size_t)g * U * C;
#pragma unroll
    for (int q = 0; q < U / 4; ++q)
      gload16(xr + (size_t)q * 4 * C, &ring[sl][0][q * 4][0]);
#pragma unroll
    for (int q = 0; q < U / 4; ++q)
      gload16(yr + (size_t)q * 4 * C, &ring[sl][1][q * 4][0]);
  };

  issue(0); issue(1); issue(2); issue(3);

#pragma unroll 1
  for (int g = 0; g < NG; ++g) {
    const int rem = NG - 1 - g;
    if (rem >= 3)      vwait48();   // 3 younger groups (48 loads) outstanding-max
    else if (rem == 2) vwait32();
    else if (rem == 1) vwait16();
    else               vwait0();

    const int sl = g & (G - 1);
#pragma unroll
    for (int r = 0; r < U; ++r) {
      float xv = ring[sl][0][r][lane];
      float yv = ring[sl][1][r][lane];
      Y0 = rintf(fmaf(ALPHA, Y0, Kc * xv));   // 24b EMA (scaled)
      Y1 = rintf(fmaf(ALPHA, Y1, Kc * yv));
      if (g >= WG) {
        float o = (rintf(Y0 * C8) + rintf(Y1 * C8)) * I16;
        __builtin_nontemporal_store(o, op + (size_t)(g - WG) * U * C + (size_t)r * C);
      }
    }

    if (g + G < NG) {
      lwait0();          // slot sl's ds_reads landed in VGPRs
      issue(g + G);      // safe to DMA-overwrite slot sl
    }
  }
}

__global__ __launch_bounds__(64) void I24DualEMA_kernel(const float* __restrict__ x,
                                                        const float* __restrict__ y,
                                                        float* __restrict__ out) {
  __shared__ float ring[G][2][U][64];   // 64 KB
  const int lane  = threadIdx.x;
  const int bid   = blockIdx.x;              // 256 blocks: [b(4)|chunk(2)|cq(2)]
  const int cq    = bid & (CQ - 1);
  const int chunk = (bid >> 2) & (NCHUNK - 1);
  const int b     = bid >> 4;
  const long t0   = (long)chunk * S;
  const long tin  = chunk ? (t0 - W) : 0;

  // per-lane gl_lds source offset: row (lane>>4) of the quad, 16B chunk (lane&15)
  const int laneOff = (lane >> 4) * C + (lane & 15) * 4;
  const size_t inBase  = ((size_t)b * T + tin) * C + cq * 64;
  const size_t outBase = ((size_t)b * T + t0)  * C + cq * 64 + lane;

  if (chunk == 0)
    run_chunk<false>(x + inBase + laneOff, y + inBase + laneOff, out + outBase, ring, lane);
  else
    run_chunk<true>(x + inBase + laneOff, y + inBase + laneOff, out + outBase, ring, lane);
}

extern "C" void kernel_launch(void* const* d_in, const int* in_sizes, int n_in,
                              void* d_out, int out_size, void* d_ws, size_t ws_size,
                              hipStream_t stream) {
  const float* x = (const float*)d_in[0];
  const float* y = (const float*)d_in[1];
  float* out = (float*)d_out;
  const int B = in_sizes[0] / (T * C);       // 16
  const int nblocks = B * NCHUNK * CQ;       // 256
  I24DualEMA_kernel<<<dim3(nblocks), dim3(64), 0, stream>>>(x, y, out);
}

// Round 8
// 65.883 us; speedup vs baseline: 2.2219x; 2.2219x over previous
//
#include <hip/hip_runtime.h>

// Dual quantized EMA scan, chunked with redundant warmup.
// State in scaled domain Y = y*2^23: 24-bit quantize = one v_rndne.
// R8 = revert to R6 (best verified: 66.2 us). R7 falsified the "1 wave/CU
// can sustain demand BW" hypothesis (146 us at 2.8 TB/s demand): the 6.4 TB/s
// demand ceiling requires >=2 waves/CU AND >=32 KB/CU in flight. R6 sits at
// demand 427 MB / 6.45 TB/s = measured ceiling; unique-traffic floor is
// 402 MB -> 62.8 us, gap ~5% (warmup amp 1.094, irreducible without
// serializing cross-chunk state handoff).
//
// Structure: S=1024, W=96, 512 blocks (16 B x 8 chunks x 4 row-quarters),
// 1 wave each, 1 float/lane, U=32 rows/group register-double-buffered
// (16 KB/wave in flight), warmup peeled (WG=3 odd).

constexpr int T = 8192;
constexpr int C = 256;
constexpr int S = 1024;         // chunk length (output rows per block)
constexpr int W = 96;           // warmup length (alpha^96*|state| ~ 5e-4)
constexpr int U = 32;           // rows per load/compute group
constexpr int NCHUNK = T / S;   // 8
constexpr int CSPLIT = 4;       // row split: 64 floats per wave
constexpr int WG = W / U;       // 3 warmup groups
constexpr int NG = WG + S / U;  // 35 total groups

constexpr float ALPHA = 0.95f;

__device__ __forceinline__ void load_group(const float* __restrict__ xq,
                                           const float* __restrict__ yq,
                                           float* xv, float* yv) {
#pragma unroll
  for (int i = 0; i < U; ++i) {
    xv[i] = xq[(size_t)i * C];
    yv[i] = yq[(size_t)i * C];
  }
}

template <bool STORE>
__device__ __forceinline__ void proc_group(float& Y0, float& Y1,
                                           const float* xv, const float* yv,
                                           float* __restrict__ oq) {
  const float K   = (1.0f - ALPHA) * 8388608.0f;  // (1-a) * 2^23
  const float C8  = 1.0f / 256.0f;                // 2^23 -> 2^15 domain
  const float I16 = 1.0f / 32768.0f;
#pragma unroll
  for (int i = 0; i < U; ++i) {
    Y0 = rintf(fmaf(ALPHA, Y0, K * xv[i]));   // 24b EMA (scaled)
    Y1 = rintf(fmaf(ALPHA, Y1, K * yv[i]));
    if (STORE) {
      float o = (rintf(Y0 * C8) + rintf(Y1 * C8)) * I16;
      __builtin_nontemporal_store(o, &oq[(size_t)i * C]);
    }
  }
}

template <bool WARM>
__device__ __forceinline__ void run_chunk(const float* __restrict__ xp,
                                          const float* __restrict__ yp,
                                          float* __restrict__ op) {
  float xa[U], ya[U], xb[U], yb[U];
  float Y0 = 0.0f, Y1 = 0.0f;

  auto xg = [&](int g) { return xp + (size_t)g * U * C; };
  auto yg = [&](int g) { return yp + (size_t)g * U * C; };

  if (WARM) {
    // Peeled warmup: groups 0,1,2 (WG=3). After this, b holds g=3, a holds g=4.
    load_group(xg(0), yg(0), xa, ya);
    load_group(xg(1), yg(1), xb, yb);
    proc_group<false>(Y0, Y1, xa, ya, nullptr);
    load_group(xg(2), yg(2), xa, ya);
    proc_group<false>(Y0, Y1, xb, yb, nullptr);
    load_group(xg(3), yg(3), xb, yb);
    proc_group<false>(Y0, Y1, xa, ya, nullptr);
    load_group(xg(4), yg(4), xa, ya);

#pragma unroll 1
    for (int g = WG; g < NG; g += 2) {     // g = 3,5,...,33 (b holds g, a holds g+1)
      proc_group<true>(Y0, Y1, xb, yb, op + (size_t)(g - WG) * U * C);
      if (g + 2 < NG) load_group(xg(g + 2), yg(g + 2), xb, yb);
      proc_group<true>(Y0, Y1, xa, ya, op + (size_t)(g + 1 - WG) * U * C);
      if (g + 3 < NG) load_group(xg(g + 3), yg(g + 3), xa, ya);
    }
  } else {
    // chunk 0: 32 groups, even pairs.
    load_group(xg(0), yg(0), xa, ya);
#pragma unroll 1
    for (int g = 0; g < NG - WG; g += 2) {
      load_group(xg(g + 1), yg(g + 1), xb, yb);
      proc_group<true>(Y0, Y1, xa, ya, op + (size_t)g * U * C);
      if (g + 2 < NG - WG) load_group(xg(g + 2), yg(g + 2), xa, ya);
      proc_group<true>(Y0, Y1, xb, yb, op + (size_t)(g + 1) * U * C);
    }
  }
}

__global__ __launch_bounds__(64) void I24DualEMA_kernel(const float* __restrict__ x,
                                                        const float* __restrict__ y,
                                                        float* __restrict__ out) {
  const int lane  = threadIdx.x;             // 0..63 -> float column within quarter
  const int bid   = blockIdx.x;
  const int cq    = bid & (CSPLIT - 1);
  const int chunk = (bid >> 2) & (NCHUNK - 1);
  const int b     = bid >> 5;
  const int col   = (cq << 6) | lane;
  const long t0   = (long)chunk * S;

  if (chunk == 0) {
    const size_t base = (size_t)b * T * C + col;
    run_chunk<false>(x + base, y + base, out + base);
  } else {
    const size_t baseIn  = ((size_t)b * T + (t0 - W)) * C + col;
    const size_t baseOut = ((size_t)b * T + t0) * C + col;
    run_chunk<true>(x + baseIn, y + baseIn, out + baseOut);
  }
}

extern "C" void kernel_launch(void* const* d_in, const int* in_sizes, int n_in,
                              void* d_out, int out_size, void* d_ws, size_t ws_size,
                              hipStream_t stream) {
  const float* x = (const float*)d_in[0];
  const float* y = (const float*)d_in[1];
  float* out = (float*)d_out;
  const int B = in_sizes[0] / (T * C);          // 16
  const int nblocks = B * NCHUNK * CSPLIT;      // 512
  I24DualEMA_kernel<<<dim3(nblocks), dim3(64), 0, stream>>>(x, y, out);
}